// Round 19
// baseline (285.551 us; speedup 1.0000x reference)
//
#include <hip/hip_runtime.h>
#include <hip/hip_cooperative_groups.h>

namespace cg = cooperative_groups;

// Problem constants (B,S,H,D fixed by the reference)
#define BB   2
#define SS   2048
#define HH   16
#define DD   64
#define CC   128               // chunk length
#define NCH  (SS/CC)           // 16 chunks per (b,h)
#define RECF (DD*DD + DD)      // 4160 elems per record: State^T rows 0..63 + ksum row 64
#define BHN  (BB*HH)           // 32
#define NCHK (BHN*NCH)         // 512 chunk-blocks

typedef __attribute__((ext_vector_type(8))) short short8;
typedef __attribute__((ext_vector_type(4))) float f32x4;

// XOR swizzle of the s-index (units of 8 shorts) by LDS row (stride-136 tiles).
#define SW(r) ((((r) >> 3) & 7) << 3)
// XOR swizzle for the pad-free Kbh[64][64] tile (fallback k_out).
#define SK(r) (((r) & 7) << 3)

__device__ __forceinline__ float elu1(float x) {
    return x > 0.0f ? x + 1.0f : __expf(x);
}
__device__ __forceinline__ short f2bf(float f) {
    union { float f; unsigned u; } x; x.f = f;
    unsigned r = x.u + 0x7FFFu + ((x.u >> 16) & 1u);   // RNE
    return (short)(r >> 16);
}
__device__ __forceinline__ float bf2f(short s) {
    union { unsigned u; float f; } x; x.u = ((unsigned)(unsigned short)s) << 16;
    return x.f;
}
__device__ __forceinline__ unsigned pack2(float lo, float hi) {
    return (unsigned)(unsigned short)f2bf(lo)
         | ((unsigned)(unsigned short)f2bf(hi) << 16);
}

// ===========================================================================
// Fused one-sync cooperative kernel.
// LDS (shorts): [0,8704) KT[64][136] (A) / Sbh[128][68] (B)
//               [8704,13384)  StT[65][72]
//               [13384,22224) VT[65][136]  (persists A->B)
//               [22224,31440) Kb[128][72]  (written A, read B)
// total 31440 shorts = 62,880 B <= 64 KB coop cap; 2 blocks/CU.
// ===========================================================================
#define OFF_ST 8704
#define OFF_VT 13384
#define OFF_KB 22224
#define NSMEM  31440

__global__ __launch_bounds__(512) void k_fused(const float* __restrict__ qk,
                                               const float* __restrict__ v,
                                               short* __restrict__ rec_g,
                                               float* __restrict__ out) {
    const int blk = blockIdx.x;
    const int c   = blk % NCH;
    const int bh  = blk / NCH;
    const int b = bh / HH, h = bh % HH;
    const int tid = threadIdx.x;
    const int w   = tid >> 6;
    const int l   = tid & 63;
    const int l15 = l & 15;
    const int g   = l >> 4;

    __shared__ __align__(16) short smem[NSMEM];
    short (*KT) [136] = (short(*)[136])(smem);
    short (*Sbh)[68]  = (short(*)[68]) (smem);
    short (*StT)[72]  = (short(*)[72]) (smem + OFF_ST);
    short (*VT) [136] = (short(*)[136])(smem + OFF_VT);
    short (*Kb) [72]  = (short(*)[72]) (smem + OFF_KB);

    // ============ Phase A: stage K (KT + Kb) and V (VT), compute state ======
#pragma unroll
    for (int it = 0; it < 2; ++it) {
        const int pi   = tid + it*512;      // 0..1023
        const int r    = pi >> 4;           // row-pair index
        const int col4 = (pi & 15) * 4;     // d base
        const int s0 = c*CC + 2*r;
        const float* kp = qk + ((((size_t)b*SS + s0)*2 + 1)*HH + h)*DD + col4;
        float4 k0 = *(const float4*)kp;
        float4 k1 = *(const float4*)(kp + 2*HH*DD);
        const float* vp = v + (((size_t)b*SS + s0)*HH + h)*DD + col4;
        float4 v0 = *(const float4*)vp;
        float4 v1 = *(const float4*)(vp + HH*DD);
        const int s2 = 2*r;
        // elu'd K, shared by KT and Kb
        const float e0x=elu1(k0.x), e0y=elu1(k0.y), e0z=elu1(k0.z), e0w=elu1(k0.w);
        const float e1x=elu1(k1.x), e1y=elu1(k1.y), e1z=elu1(k1.z), e1w=elu1(k1.w);
        *(unsigned*)(&KT[col4+0][s2 ^ SW(col4+0)]) = pack2(e0x, e1x);
        *(unsigned*)(&KT[col4+1][s2 ^ SW(col4+1)]) = pack2(e0y, e1y);
        *(unsigned*)(&KT[col4+2][s2 ^ SW(col4+2)]) = pack2(e0z, e1z);
        *(unsigned*)(&KT[col4+3][s2 ^ SW(col4+3)]) = pack2(e0w, e1w);
        short4 kbA; kbA.x=f2bf(e0x); kbA.y=f2bf(e0y); kbA.z=f2bf(e0z); kbA.w=f2bf(e0w);
        short4 kbB; kbB.x=f2bf(e1x); kbB.y=f2bf(e1y); kbB.z=f2bf(e1z); kbB.w=f2bf(e1w);
        *(short4*)(&Kb[s2    ][col4]) = kbA;
        *(short4*)(&Kb[s2 + 1][col4]) = kbB;
        *(unsigned*)(&VT[col4+0][s2 ^ SW(col4+0)]) = pack2(v0.x, v1.x);
        *(unsigned*)(&VT[col4+1][s2 ^ SW(col4+1)]) = pack2(v0.y, v1.y);
        *(unsigned*)(&VT[col4+2][s2 ^ SW(col4+2)]) = pack2(v0.z, v1.z);
        *(unsigned*)(&VT[col4+3][s2 ^ SW(col4+3)]) = pack2(v0.w, v1.w);
    }
    if (tid < 64) *(unsigned*)(&VT[64][2*tid]) = 0x3F803F80u;   // ones row (SW(64)==0)

    // early Q loads (raw fp32), consumed in phase B
    const int qrow = 16*w + l15;
    const float* qp = qk + ((((size_t)b*SS + (c*CC + qrow))*2 + 0)*HH + h)*DD;
    float4 q0 = *(const float4*)(qp + 8*g);
    float4 q1 = *(const float4*)(qp + 8*g + 4);
    float4 q2 = *(const float4*)(qp + 32 + 8*g);
    float4 q3 = *(const float4*)(qp + 32 + 8*g + 4);

    __syncthreads();

    // state MFMA (R15 k_state): d-tile = w&3, rt half split 3/2
    {
        const int dtile = w & 3;
        const int half  = w >> 2;
        const int nrt   = half ? 2 : 3;
        const int rt0   = half ? 3 : 0;
        f32x4 acc1[3];
#pragma unroll
        for (int i = 0; i < 3; ++i) acc1[i] = (f32x4){0.f,0.f,0.f,0.f};
        const int krow = 16*dtile + l15;
#pragma unroll
        for (int ks = 0; ks < 4; ++ks) {
            const int cb = 32*ks + 8*g;
            short8 bk = *(const short8*)(&KT[krow][cb ^ SW(krow)]);
#pragma unroll
            for (int i = 0; i < 3; ++i) {
                if (i < nrt) {
                    int arow = 16*(rt0 + i) + l15;
                    if (arow > 64) arow = 64;          // clamp into ones row
                    short8 a = *(const short8*)(&VT[arow][cb ^ SW(arow)]);
                    acc1[i] = __builtin_amdgcn_mfma_f32_16x16x32_bf16(a, bk, acc1[i], 0, 0, 0);
                }
            }
        }
        short* rec = rec_g + (size_t)blk * RECF;
#pragma unroll
        for (int i = 0; i < 3; ++i) {
            if (i < nrt) {
                const int rt = rt0 + i;
                if (rt < 4) {
#pragma unroll
                    for (int e = 0; e < 4; ++e)
                        rec[(16*rt + 4*g + e)*DD + 16*dtile + l15] = f2bf(acc1[i][e]);
                } else if (g == 0) {
                    rec[4096 + 16*dtile + l15] = f2bf(acc1[i][0]);   // ksum row
                }
            }
        }
    }

    __threadfence();
    cg::this_grid().sync();
    __threadfence();

    // ============ Phase B: O = [S | Q].[V;ones ; StT;ksum] ==================
    // lookback loads (R12 flat clamped pattern), consumed after S-A MFMAs
    const short* base = rec_g + (size_t)(bh*NCH) * RECF;
    short8 rv[15];
#pragma unroll
    for (int p = 0; p < 15; ++p) {
        const int pp = (p < c) ? p : 0;
        rv[p] = *(const short8*)(base + (size_t)pp*RECF + tid*8);
    }
    short ksv[15];
    if (tid < 64) {
#pragma unroll
        for (int p = 0; p < 15; ++p) {
            const int pp = (p < c) ? p : 0;
            ksv[p] = base[(size_t)pp*RECF + 4096 + tid];
        }
    }

    // Q fragments from prefetched regs
    short8 aq[2];
    {
        short8 a;
        a[0]=f2bf(elu1(q0.x)); a[1]=f2bf(elu1(q0.y)); a[2]=f2bf(elu1(q0.z)); a[3]=f2bf(elu1(q0.w));
        a[4]=f2bf(elu1(q1.x)); a[5]=f2bf(elu1(q1.y)); a[6]=f2bf(elu1(q1.z)); a[7]=f2bf(elu1(q1.w));
        aq[0] = a;
        a[0]=f2bf(elu1(q2.x)); a[1]=f2bf(elu1(q2.y)); a[2]=f2bf(elu1(q2.z)); a[3]=f2bf(elu1(q2.w));
        a[4]=f2bf(elu1(q3.x)); a[5]=f2bf(elu1(q3.y)); a[6]=f2bf(elu1(q3.z)); a[7]=f2bf(elu1(q3.w));
        aq[1] = a;
    }

    const int rowb = 16*w + 4*g;

    // ---- S pass A: cols 0..63 (Kb rows 0..63) -> Sbh ----
#pragma unroll
    for (int tc = 0; tc < 4; ++tc) {
        f32x4 sacc = {0.f,0.f,0.f,0.f};
#pragma unroll
        for (int ks = 0; ks < 2; ++ks) {
            short8 bk = *(const short8*)(&Kb[16*tc + l15][32*ks + 8*g]);
            sacc = __builtin_amdgcn_mfma_f32_16x16x32_bf16(aq[ks], bk, sacc, 0, 0, 0);
        }
        const int colg = 16*tc + l15;
#pragma unroll
        for (int e = 0; e < 4; ++e) {
            const float sv = (colg <= rowb + e) ? sacc[e] : 0.0f;
            Sbh[rowb + e][colg] = f2bf(sv);
        }
    }
    __syncthreads();   // (a) Sbh-A ready

    // ---- deferred lookback accumulate -> StT (ascending p, bit-identical) --
    {
        float pf[8] = {0.f,0.f,0.f,0.f,0.f,0.f,0.f,0.f};
#pragma unroll
        for (int p = 0; p < 15; ++p) {
            if (p < c) {
#pragma unroll
                for (int e = 0; e < 8; ++e) pf[e] += bf2f(rv[p][e]);
            }
        }
        short8 sv;
#pragma unroll
        for (int e = 0; e < 8; ++e) sv[e] = f2bf(pf[e]);
        *(short8*)(&StT[tid >> 3][(tid & 7) * 8]) = sv;
        if (tid < 64) {
            float ps = 0.f;
#pragma unroll
            for (int p = 0; p < 15; ++p)
                if (p < c) ps += bf2f(ksv[p]);
            StT[64][tid] = f2bf(ps);
        }
    }

    // ---- O = S_A.V (kj 0,1); tile 4 = denominator column ----
    f32x4 acc[5];
#pragma unroll
    for (int t = 0; t < 5; ++t) acc[t] = (f32x4){0.f,0.f,0.f,0.f};
#pragma unroll
    for (int kj = 0; kj < 2; ++kj) {
        short8 as = *(const short8*)(&Sbh[16*w + l15][32*kj + 8*g]);
#pragma unroll
        for (int tc = 0; tc < 5; ++tc) {
            int vrow = 16*tc + l15;
            if (vrow > 64) vrow = 64;              // clamp into ones row
            short8 bv = *(const short8*)(&VT[vrow][(32*kj + 8*g) ^ SW(vrow)]);
            acc[tc] = __builtin_amdgcn_mfma_f32_16x16x32_bf16(as, bv, acc[tc], 0, 0, 0);
        }
    }
    __syncthreads();   // (b) StT visible; Sbh-A reads done

    // ---- S pass B: cols 64..127 (Kb rows 64..127) -> Sbh (local col-64) ----
#pragma unroll
    for (int tc = 4; tc < 8; ++tc) {
        f32x4 sacc = {0.f,0.f,0.f,0.f};
#pragma unroll
        for (int ks = 0; ks < 2; ++ks) {
            short8 bk = *(const short8*)(&Kb[16*tc + l15][32*ks + 8*g]);
            sacc = __builtin_amdgcn_mfma_f32_16x16x32_bf16(aq[ks], bk, sacc, 0, 0, 0);
        }
        const int colg = 16*tc + l15;
#pragma unroll
        for (int e = 0; e < 4; ++e) {
            const float sv = (colg <= rowb + e) ? sacc[e] : 0.0f;
            Sbh[rowb + e][colg - 64] = f2bf(sv);
        }
    }

    // ---- O += Q . State^T (kd 0,1) ----
#pragma unroll
    for (int kd = 0; kd < 2; ++kd) {
#pragma unroll
        for (int tc = 0; tc < 5; ++tc) {
            int srow = 16*tc + l15;
            if (srow > 64) srow = 64;              // clamp into ksum row
            short8 bs = *(const short8*)(&StT[srow][32*kd + 8*g]);
            acc[tc] = __builtin_amdgcn_mfma_f32_16x16x32_bf16(aq[kd], bs, acc[tc], 0, 0, 0);
        }
    }
    __syncthreads();   // (c) Sbh-B ready

    // ---- O += S_B.V (kj 2,3) ----
#pragma unroll
    for (int kj = 2; kj < 4; ++kj) {
        short8 as = *(const short8*)(&Sbh[16*w + l15][32*(kj-2) + 8*g]);
#pragma unroll
        for (int tc = 0; tc < 5; ++tc) {
            int vrow = 16*tc + l15;
            if (vrow > 64) vrow = 64;
            short8 bv = *(const short8*)(&VT[vrow][(32*kj + 8*g) ^ SW(vrow)]);
            acc[tc] = __builtin_amdgcn_mfma_f32_16x16x32_bf16(as, bv, acc[tc], 0, 0, 0);
        }
    }

    // ---- epilogue ----
    float rn[4];
#pragma unroll
    for (int e = 0; e < 4; ++e) rn[e] = 1.0f / acc[4][e];
    const int rowg = c*CC + rowb;
#pragma unroll
    for (int e = 0; e < 4; ++e) {
        float* orow = out + (((size_t)b*SS + rowg + e)*HH + h)*DD + l15;
#pragma unroll
        for (int tc = 0; tc < 4; ++tc) orow[16*tc] = acc[tc][e] * rn[e];
    }
}

// ===========================================================================
// Fallback path: verbatim R15 3-kernel pipeline (30.0 µs, proven).
// ===========================================================================
__global__ __launch_bounds__(512) void k_state_fb(const float* __restrict__ qk,
                                                  const float* __restrict__ v,
                                                  short* __restrict__ rec_g) {
    const int blk = blockIdx.x;
    const int c   = blk % NCH;
    const int bh  = blk / NCH;
    const int b = bh / HH, h = bh % HH;
    const int tid = threadIdx.x;
    const int w   = tid >> 6;
    const int l   = tid & 63;
    const int l15 = l & 15;
    const int g   = l >> 4;

    __shared__ short KT[64][136];
    __shared__ short VT[65][136];

#pragma unroll
    for (int it = 0; it < 2; ++it) {
        const int pi   = tid + it*512;
        const int r    = pi >> 4;
        const int col4 = (pi & 15) * 4;
        const int s0 = c*CC + 2*r;
        const float* kp = qk + ((((size_t)b*SS + s0)*2 + 1)*HH + h)*DD + col4;
        float4 k0 = *(const float4*)kp;
        float4 k1 = *(const float4*)(kp + 2*HH*DD);
        const float* vp = v + (((size_t)b*SS + s0)*HH + h)*DD + col4;
        float4 v0 = *(const float4*)vp;
        float4 v1 = *(const float4*)(vp + HH*DD);
        const int s2 = 2*r;
        *(unsigned*)(&KT[col4+0][s2 ^ SW(col4+0)]) = pack2(elu1(k0.x), elu1(k1.x));
        *(unsigned*)(&KT[col4+1][s2 ^ SW(col4+1)]) = pack2(elu1(k0.y), elu1(k1.y));
        *(unsigned*)(&KT[col4+2][s2 ^ SW(col4+2)]) = pack2(elu1(k0.z), elu1(k1.z));
        *(unsigned*)(&KT[col4+3][s2 ^ SW(col4+3)]) = pack2(elu1(k0.w), elu1(k1.w));
        *(unsigned*)(&VT[col4+0][s2 ^ SW(col4+0)]) = pack2(v0.x, v1.x);
        *(unsigned*)(&VT[col4+1][s2 ^ SW(col4+1)]) = pack2(v0.y, v1.y);
        *(unsigned*)(&VT[col4+2][s2 ^ SW(col4+2)]) = pack2(v0.z, v1.z);
        *(unsigned*)(&VT[col4+3][s2 ^ SW(col4+3)]) = pack2(v0.w, v1.w);
    }
    if (tid < 64) *(unsigned*)(&VT[64][2*tid]) = 0x3F803F80u;
    __syncthreads();

    const int dtile = w & 3;
    const int half  = w >> 2;
    const int nrt   = half ? 2 : 3;
    const int rt0   = half ? 3 : 0;
    f32x4 acc1[3];
#pragma unroll
    for (int i = 0; i < 3; ++i) acc1[i] = (f32x4){0.f,0.f,0.f,0.f};
    const int krow = 16*dtile + l15;
#pragma unroll
    for (int ks = 0; ks < 4; ++ks) {
        const int cb = 32*ks + 8*g;
        short8 bk = *(const short8*)(&KT[krow][cb ^ SW(krow)]);
#pragma unroll
        for (int i = 0; i < 3; ++i) {
            if (i < nrt) {
                int arow = 16*(rt0 + i) + l15;
                if (arow > 64) arow = 64;
                short8 a = *(const short8*)(&VT[arow][cb ^ SW(arow)]);
                acc1[i] = __builtin_amdgcn_mfma_f32_16x16x32_bf16(a, bk, acc1[i], 0, 0, 0);
            }
        }
    }
    short* rec = rec_g + (size_t)blk * RECF;
#pragma unroll
    for (int i = 0; i < 3; ++i) {
        if (i < nrt) {
            const int rt = rt0 + i;
            if (rt < 4) {
#pragma unroll
                for (int e = 0; e < 4; ++e)
                    rec[(16*rt + 4*g + e)*DD + 16*dtile + l15] = f2bf(acc1[i][e]);
            } else if (g == 0) {
                rec[4096 + 16*dtile + l15] = f2bf(acc1[i][0]);
            }
        }
    }
}

__global__ __launch_bounds__(256) void k_scan_fb(const short* __restrict__ rec_g,
                                                 short* __restrict__ stp_g) {
    const int bh    = blockIdx.x >> 4;
    const int slice = blockIdx.x & 15;
#pragma unroll 1
    for (int ee = threadIdx.x; ee < 260; ee += 256) {
        const int elem = slice*260 + ee;
        float vals[16];
#pragma unroll
        for (int c2 = 0; c2 < 16; ++c2)
            vals[c2] = bf2f(rec_g[(size_t)(bh*NCH + c2)*RECF + elem]);
        float pref = 0.0f;
#pragma unroll
        for (int c2 = 0; c2 < 16; ++c2) {
            stp_g[(size_t)(bh*NCH + c2)*RECF + elem] = f2bf(pref);
            pref += vals[c2];
        }
    }
}

__global__ __launch_bounds__(512) void k_out_fb(const float* __restrict__ qk,
                                                const float* __restrict__ v,
                                                const short* __restrict__ stp_g,
                                                float* __restrict__ out) {
    const int blk = blockIdx.x;
    const int c   = blk % NCH;
    const int bh  = blk / NCH;
    const int b = bh / HH, h = bh % HH;
    const int tid = threadIdx.x;
    const int w   = tid >> 6;
    const int l   = tid & 63;
    const int l15 = l & 15;
    const int g   = l >> 4;

    __shared__ short Kbh[64][64];
    __shared__ short Sbh[128][72];
    __shared__ short StT[65][72];
    __shared__ short VT[65][136];

#pragma unroll
    for (int it = 0; it < 2; ++it) {
        const int pi   = tid + it*512;
        const int r    = pi >> 4;
        const int col4 = (pi & 15) * 4;
        const int s0 = c*CC + 2*r;
        const float* vp = v + (((size_t)b*SS + s0)*HH + h)*DD + col4;
        float4 v0 = *(const float4*)vp;
        float4 v1 = *(const float4*)(vp + HH*DD);
        const int s2 = 2*r;
        *(unsigned*)(&VT[col4+0][s2 ^ SW(col4+0)]) = pack2(v0.x, v1.x);
        *(unsigned*)(&VT[col4+1][s2 ^ SW(col4+1)]) = pack2(v0.y, v1.y);
        *(unsigned*)(&VT[col4+2][s2 ^ SW(col4+2)]) = pack2(v0.z, v1.z);
        *(unsigned*)(&VT[col4+3][s2 ^ SW(col4+3)]) = pack2(v0.w, v1.w);
    }
    if (tid < 64) *(unsigned*)(&VT[64][2*tid]) = 0x3F803F80u;

#pragma unroll
    for (int it = 0; it < 2; ++it) {
        const int f    = tid + it*512;
        const int row  = f >> 4;
        const int col4 = (f & 15) * 4;
        const int s = c*CC + row;
        float4 kq = *(const float4*)(qk + ((((size_t)b*SS + s)*2 + 1)*HH + h)*DD + col4);
        short4 kb;
        kb.x = f2bf(elu1(kq.x)); kb.y = f2bf(elu1(kq.y));
        kb.z = f2bf(elu1(kq.z)); kb.w = f2bf(elu1(kq.w));
        *(short4*)(&Kbh[row][col4 ^ SK(row)]) = kb;
    }

    short4 kbB[2];
#pragma unroll
    for (int it = 0; it < 2; ++it) {
        const int f    = tid + it*512;
        const int row  = 64 + (f >> 4);
        const int col4 = (f & 15) * 4;
        const int s = c*CC + row;
        float4 kq = *(const float4*)(qk + ((((size_t)b*SS + s)*2 + 1)*HH + h)*DD + col4);
        kbB[it].x = f2bf(elu1(kq.x)); kbB[it].y = f2bf(elu1(kq.y));
        kbB[it].z = f2bf(elu1(kq.z)); kbB[it].w = f2bf(elu1(kq.w));
    }

    {
        const short* stp = stp_g + (size_t)blk * RECF;
        short8 st0 = *(const short8*)(stp + tid*8);
        *(short8*)(&StT[tid >> 3][(tid & 7) * 8]) = st0;
        if (tid < 8) {
            short8 st1 = *(const short8*)(stp + 4096 + tid*8);
            *(short8*)(&StT[64][tid * 8]) = st1;
        }
    }

    const int qrow = 16*w + l15;
    const float* qp = qk + ((((size_t)b*SS + (c*CC + qrow))*2 + 0)*HH + h)*DD;
    short8 aq[2];
#pragma unroll
    for (int ks = 0; ks < 2; ++ks) {
        const int k0 = 32*ks + 8*g;
        float4 t0 = *(const float4*)(qp + k0);
        float4 t1 = *(const float4*)(qp + k0 + 4);
        short8 a;
        a[0] = f2bf(elu1(t0.x)); a[1] = f2bf(elu1(t0.y));
        a[2] = f2bf(elu1(t0.z)); a[3] = f2bf(elu1(t0.w));
        a[4] = f2bf(elu1(t1.x)); a[5] = f2bf(elu1(t1.y));
        a[6] = f2bf(elu1(t1.z)); a[7] = f2bf(elu1(t1.w));
        aq[ks] = a;
    }
    __syncthreads();

    const int rowb = 16*w + 4*g;

#pragma unroll
    for (int tc = 0; tc < 4; ++tc) {
        const int kr = 16*tc + l15;
        f32x4 sacc = {0.f,0.f,0.f,0.f};
#pragma unroll
        for (int ks = 0; ks < 2; ++ks) {
            short8 bk = *(const short8*)(&Kbh[kr][(32*ks + 8*g) ^ SK(kr)]);
            sacc = __builtin_amdgcn_mfma_f32_16x16x32_bf16(aq[ks], bk, sacc, 0, 0, 0);
        }
        const int colg = 16*tc + l15;
#pragma unroll
        for (int e = 0; e < 4; ++e) {
            const float sv = (colg <= rowb + e) ? sacc[e] : 0.0f;
            Sbh[rowb + e][colg] = f2bf(sv);
        }
    }
    __syncthreads();

#pragma unroll
    for (int it = 0; it < 2; ++it) {
        const int f    = tid + it*512;
        const int row  = f >> 4;
        const int col4 = (f & 15) * 4;
        *(short4*)(&Kbh[row][col4 ^ SK(row)]) = kbB[it];
    }

    f32x4 acc[5];
#pragma unroll
    for (int t = 0; t < 5; ++t) acc[t] = (f32x4){0.f,0.f,0.f,0.f};
#pragma unroll
    for (int kj = 0; kj < 2; ++kj) {
        short8 as = *(const short8*)(&Sbh[16*w + l15][32*kj + 8*g]);
#pragma unroll
        for (int tc = 0; tc < 5; ++tc) {
            int vrow = 16*tc + l15;
            if (vrow > 64) vrow = 64;
            short8 bv = *(const short8*)(&VT[vrow][(32*kj + 8*g) ^ SW(vrow)]);
            acc[tc] = __builtin_amdgcn_mfma_f32_16x16x32_bf16(as, bv, acc[tc], 0, 0, 0);
        }
    }
#pragma unroll
    for (int kd = 0; kd < 2; ++kd) {
#pragma unroll
        for (int tc = 0; tc < 5; ++tc) {
            int srow = 16*tc + l15;
            if (srow > 64) srow = 64;
            short8 bs = *(const short8*)(&StT[srow][32*kd + 8*g]);
            acc[tc] = __builtin_amdgcn_mfma_f32_16x16x32_bf16(aq[kd], bs, acc[tc], 0, 0, 0);
        }
    }
    __syncthreads();

#pragma unroll
    for (int tc = 4; tc < 8; ++tc) {
        const int kr = 16*(tc-4) + l15;
        f32x4 sacc = {0.f,0.f,0.f,0.f};
#pragma unroll
        for (int ks = 0; ks < 2; ++ks) {
            short8 bk = *(const short8*)(&Kbh[kr][(32*ks + 8*g) ^ SK(kr)]);
            sacc = __builtin_amdgcn_mfma_f32_16x16x32_bf16(aq[ks], bk, sacc, 0, 0, 0);
        }
        const int colg = 16*tc + l15;
#pragma unroll
        for (int e = 0; e < 4; ++e) {
            const float sv = (colg <= rowb + e) ? sacc[e] : 0.0f;
            Sbh[rowb + e][colg - 64] = f2bf(sv);
        }
    }
    __syncthreads();

#pragma unroll
    for (int kj = 2; kj < 4; ++kj) {
        short8 as = *(const short8*)(&Sbh[16*w + l15][32*(kj-2) + 8*g]);
#pragma unroll
        for (int tc = 0; tc < 5; ++tc) {
            int vrow = 16*tc + l15;
            if (vrow > 64) vrow = 64;
            short8 bv = *(const short8*)(&VT[vrow][(32*kj + 8*g) ^ SW(vrow)]);
            acc[tc] = __builtin_amdgcn_mfma_f32_16x16x32_bf16(as, bv, acc[tc], 0, 0, 0);
        }
    }

    float rn[4];
#pragma unroll
    for (int e = 0; e < 4; ++e) rn[e] = 1.0f / acc[4][e];
    const int rowg = c*CC + rowb;
#pragma unroll
    for (int e = 0; e < 4; ++e) {
        float* orow = out + (((size_t)b*SS + rowg + e)*HH + h)*DD + l15;
#pragma unroll
        for (int tc = 0; tc < 4; ++tc) orow[16*tc] = acc[tc][e] * rn[e];
    }
}

// ---------------------------------------------------------------------------
extern "C" void kernel_launch(void* const* d_in, const int* in_sizes, int n_in,
                              void* d_out, int out_size, void* d_ws, size_t ws_size,
                              hipStream_t stream) {
    const float* qk = (const float*)d_in[0];
    const float* v  = (const float*)d_in[1];
    float* out = (float*)d_out;

    short* rec_g = (short*)d_ws;                   // 512*4160 bf16 = 4.26 MB
    short* stp_g = rec_g + (size_t)NCHK * RECF;    // fallback only

    void* args[] = { (void*)&qk, (void*)&v, (void*)&rec_g, (void*)&out };
    hipError_t le = hipLaunchCooperativeKernel((const void*)k_fused, dim3(NCHK),
                                               dim3(512), args, 0, stream);
    if (le != hipSuccess) {
        k_state_fb<<<dim3(NCHK), dim3(512), 0, stream>>>(qk, v, rec_g);
        k_scan_fb <<<dim3(NCHK), dim3(256), 0, stream>>>(rec_g, stp_g);
        k_out_fb  <<<dim3(NCHK), dim3(512), 0, stream>>>(qk, v, stp_g, out);
    }
}

// Round 20
// 278.832 us; speedup vs baseline: 1.0241x; 1.0241x over previous
//
#include <hip/hip_runtime.h>
#include <hip/hip_cooperative_groups.h>

namespace cg = cooperative_groups;

// Problem constants (B,S,H,D fixed by the reference)
#define BB   2
#define SS   2048
#define HH   16
#define DD   64
#define CC   128               // chunk length
#define NCH  (SS/CC)           // 16 chunks per (b,h)
#define RECF (DD*DD + DD)      // 4160 elems per record: State^T rows 0..63 + ksum row 64
#define BHN  (BB*HH)           // 32
#define NCHK (BHN*NCH)         // 512 chunk-blocks

typedef __attribute__((ext_vector_type(8))) short short8;
typedef __attribute__((ext_vector_type(4))) float f32x4;

// XOR swizzle of the s-index (units of 8 shorts) by LDS row (stride-136 tiles).
#define SW(r) ((((r) >> 3) & 7) << 3)
// XOR swizzle for the pad-free Kbh[64][64] tile (fallback k_out).
#define SK(r) (((r) & 7) << 3)

__device__ __forceinline__ float elu1(float x) {
    return x > 0.0f ? x + 1.0f : __expf(x);
}
__device__ __forceinline__ short f2bf(float f) {
    union { float f; unsigned u; } x; x.f = f;
    unsigned r = x.u + 0x7FFFu + ((x.u >> 16) & 1u);   // RNE
    return (short)(r >> 16);
}
__device__ __forceinline__ float bf2f(short s) {
    union { unsigned u; float f; } x; x.u = ((unsigned)(unsigned short)s) << 16;
    return x.f;
}
__device__ __forceinline__ unsigned pack2(float lo, float hi) {
    return (unsigned)(unsigned short)f2bf(lo)
         | ((unsigned)(unsigned short)f2bf(hi) << 16);
}

// ===========================================================================
// Fused one-sync cooperative kernel.
// LDS (shorts): [0,8704) KT[64][136] (A) / Sbh[128][68] (B)
//               [8704,13384)  StT[65][72]
//               [13384,22224) VT[65][136]  (persists A->B)
//               [22224,31440) Kb[128][72]  (written A, read B)
// total 31440 shorts = 62,880 B <= 64 KB coop cap; 2 blocks/CU.
// __launch_bounds__(512,4): VGPR cap 128 -- rv[15] (60 VGPR) must stay in
// registers (R19's heuristic VGPR=64 spilled it to scratch: 285 us).
// ===========================================================================
#define OFF_ST 8704
#define OFF_VT 13384
#define OFF_KB 22224
#define NSMEM  31440

__global__ __launch_bounds__(512, 4) void k_fused(const float* __restrict__ qk,
                                                  const float* __restrict__ v,
                                                  short* __restrict__ rec_g,
                                                  float* __restrict__ out) {
    const int blk = blockIdx.x;
    const int c   = blk % NCH;
    const int bh  = blk / NCH;
    const int b = bh / HH, h = bh % HH;
    const int tid = threadIdx.x;
    const int w   = tid >> 6;
    const int l   = tid & 63;
    const int l15 = l & 15;
    const int g   = l >> 4;

    __shared__ __align__(16) short smem[NSMEM];
    short (*KT) [136] = (short(*)[136])(smem);
    short (*Sbh)[68]  = (short(*)[68]) (smem);
    short (*StT)[72]  = (short(*)[72]) (smem + OFF_ST);
    short (*VT) [136] = (short(*)[136])(smem + OFF_VT);
    short (*Kb) [72]  = (short(*)[72]) (smem + OFF_KB);

    // ============ Phase A: stage K (KT + Kb) and V (VT), compute state ======
#pragma unroll
    for (int it = 0; it < 2; ++it) {
        const int pi   = tid + it*512;      // 0..1023
        const int r    = pi >> 4;           // row-pair index
        const int col4 = (pi & 15) * 4;     // d base
        const int s0 = c*CC + 2*r;
        const float* kp = qk + ((((size_t)b*SS + s0)*2 + 1)*HH + h)*DD + col4;
        float4 k0 = *(const float4*)kp;
        float4 k1 = *(const float4*)(kp + 2*HH*DD);
        const float* vp = v + (((size_t)b*SS + s0)*HH + h)*DD + col4;
        float4 v0 = *(const float4*)vp;
        float4 v1 = *(const float4*)(vp + HH*DD);
        const int s2 = 2*r;
        const float e0x=elu1(k0.x), e0y=elu1(k0.y), e0z=elu1(k0.z), e0w=elu1(k0.w);
        const float e1x=elu1(k1.x), e1y=elu1(k1.y), e1z=elu1(k1.z), e1w=elu1(k1.w);
        *(unsigned*)(&KT[col4+0][s2 ^ SW(col4+0)]) = pack2(e0x, e1x);
        *(unsigned*)(&KT[col4+1][s2 ^ SW(col4+1)]) = pack2(e0y, e1y);
        *(unsigned*)(&KT[col4+2][s2 ^ SW(col4+2)]) = pack2(e0z, e1z);
        *(unsigned*)(&KT[col4+3][s2 ^ SW(col4+3)]) = pack2(e0w, e1w);
        short4 kbA; kbA.x=f2bf(e0x); kbA.y=f2bf(e0y); kbA.z=f2bf(e0z); kbA.w=f2bf(e0w);
        short4 kbB; kbB.x=f2bf(e1x); kbB.y=f2bf(e1y); kbB.z=f2bf(e1z); kbB.w=f2bf(e1w);
        *(short4*)(&Kb[s2    ][col4]) = kbA;
        *(short4*)(&Kb[s2 + 1][col4]) = kbB;
        *(unsigned*)(&VT[col4+0][s2 ^ SW(col4+0)]) = pack2(v0.x, v1.x);
        *(unsigned*)(&VT[col4+1][s2 ^ SW(col4+1)]) = pack2(v0.y, v1.y);
        *(unsigned*)(&VT[col4+2][s2 ^ SW(col4+2)]) = pack2(v0.z, v1.z);
        *(unsigned*)(&VT[col4+3][s2 ^ SW(col4+3)]) = pack2(v0.w, v1.w);
    }
    if (tid < 64) *(unsigned*)(&VT[64][2*tid]) = 0x3F803F80u;   // ones row (SW(64)==0)

    // early Q loads (raw fp32), consumed in phase B
    const int qrow = 16*w + l15;
    const float* qp = qk + ((((size_t)b*SS + (c*CC + qrow))*2 + 0)*HH + h)*DD;
    float4 q0 = *(const float4*)(qp + 8*g);
    float4 q1 = *(const float4*)(qp + 8*g + 4);
    float4 q2 = *(const float4*)(qp + 32 + 8*g);
    float4 q3 = *(const float4*)(qp + 32 + 8*g + 4);

    __syncthreads();

    // state MFMA (R15 k_state): d-tile = w&3, rt half split 3/2
    {
        const int dtile = w & 3;
        const int half  = w >> 2;
        const int nrt   = half ? 2 : 3;
        const int rt0   = half ? 3 : 0;
        f32x4 acc1[3];
#pragma unroll
        for (int i = 0; i < 3; ++i) acc1[i] = (f32x4){0.f,0.f,0.f,0.f};
        const int krow = 16*dtile + l15;
#pragma unroll
        for (int ks = 0; ks < 4; ++ks) {
            const int cb = 32*ks + 8*g;
            short8 bk = *(const short8*)(&KT[krow][cb ^ SW(krow)]);
#pragma unroll
            for (int i = 0; i < 3; ++i) {
                if (i < nrt) {
                    int arow = 16*(rt0 + i) + l15;
                    if (arow > 64) arow = 64;          // clamp into ones row
                    short8 a = *(const short8*)(&VT[arow][cb ^ SW(arow)]);
                    acc1[i] = __builtin_amdgcn_mfma_f32_16x16x32_bf16(a, bk, acc1[i], 0, 0, 0);
                }
            }
        }
        short* rec = rec_g + (size_t)blk * RECF;
#pragma unroll
        for (int i = 0; i < 3; ++i) {
            if (i < nrt) {
                const int rt = rt0 + i;
                if (rt < 4) {
#pragma unroll
                    for (int e = 0; e < 4; ++e)
                        rec[(16*rt + 4*g + e)*DD + 16*dtile + l15] = f2bf(acc1[i][e]);
                } else if (g == 0) {
                    rec[4096 + 16*dtile + l15] = f2bf(acc1[i][0]);   // ksum row
                }
            }
        }
    }

    __threadfence();
    cg::this_grid().sync();
    __threadfence();

    // ============ Phase B: O = [S | Q].[V;ones ; StT;ksum] ==================
    // lookback loads (R12 flat clamped pattern), consumed after S-A MFMAs
    const short* base = rec_g + (size_t)(bh*NCH) * RECF;
    short8 rv[15];
#pragma unroll
    for (int p = 0; p < 15; ++p) {
        const int pp = (p < c) ? p : 0;
        rv[p] = *(const short8*)(base + (size_t)pp*RECF + tid*8);
    }
    short ksv[15];
    if (tid < 64) {
#pragma unroll
        for (int p = 0; p < 15; ++p) {
            const int pp = (p < c) ? p : 0;
            ksv[p] = base[(size_t)pp*RECF + 4096 + tid];
        }
    }

    // Q fragments from prefetched regs
    short8 aq[2];
    {
        short8 a;
        a[0]=f2bf(elu1(q0.x)); a[1]=f2bf(elu1(q0.y)); a[2]=f2bf(elu1(q0.z)); a[3]=f2bf(elu1(q0.w));
        a[4]=f2bf(elu1(q1.x)); a[5]=f2bf(elu1(q1.y)); a[6]=f2bf(elu1(q1.z)); a[7]=f2bf(elu1(q1.w));
        aq[0] = a;
        a[0]=f2bf(elu1(q2.x)); a[1]=f2bf(elu1(q2.y)); a[2]=f2bf(elu1(q2.z)); a[3]=f2bf(elu1(q2.w));
        a[4]=f2bf(elu1(q3.x)); a[5]=f2bf(elu1(q3.y)); a[6]=f2bf(elu1(q3.z)); a[7]=f2bf(elu1(q3.w));
        aq[1] = a;
    }

    const int rowb = 16*w + 4*g;

    // ---- S pass A: cols 0..63 (Kb rows 0..63) -> Sbh ----
#pragma unroll
    for (int tc = 0; tc < 4; ++tc) {
        f32x4 sacc = {0.f,0.f,0.f,0.f};
#pragma unroll
        for (int ks = 0; ks < 2; ++ks) {
            short8 bk = *(const short8*)(&Kb[16*tc + l15][32*ks + 8*g]);
            sacc = __builtin_amdgcn_mfma_f32_16x16x32_bf16(aq[ks], bk, sacc, 0, 0, 0);
        }
        const int colg = 16*tc + l15;
#pragma unroll
        for (int e = 0; e < 4; ++e) {
            const float sv = (colg <= rowb + e) ? sacc[e] : 0.0f;
            Sbh[rowb + e][colg] = f2bf(sv);
        }
    }
    __syncthreads();   // (a) Sbh-A ready

    // ---- deferred lookback accumulate -> StT (ascending p, bit-identical) --
    {
        float pf[8] = {0.f,0.f,0.f,0.f,0.f,0.f,0.f,0.f};
#pragma unroll
        for (int p = 0; p < 15; ++p) {
            if (p < c) {
#pragma unroll
                for (int e = 0; e < 8; ++e) pf[e] += bf2f(rv[p][e]);
            }
        }
        short8 sv;
#pragma unroll
        for (int e = 0; e < 8; ++e) sv[e] = f2bf(pf[e]);
        *(short8*)(&StT[tid >> 3][(tid & 7) * 8]) = sv;
        if (tid < 64) {
            float ps = 0.f;
#pragma unroll
            for (int p = 0; p < 15; ++p)
                if (p < c) ps += bf2f(ksv[p]);
            StT[64][tid] = f2bf(ps);
        }
    }

    // ---- O = S_A.V (kj 0,1); tile 4 = denominator column ----
    f32x4 acc[5];
#pragma unroll
    for (int t = 0; t < 5; ++t) acc[t] = (f32x4){0.f,0.f,0.f,0.f};
#pragma unroll
    for (int kj = 0; kj < 2; ++kj) {
        short8 as = *(const short8*)(&Sbh[16*w + l15][32*kj + 8*g]);
#pragma unroll
        for (int tc = 0; tc < 5; ++tc) {
            int vrow = 16*tc + l15;
            if (vrow > 64) vrow = 64;              // clamp into ones row
            short8 bv = *(const short8*)(&VT[vrow][(32*kj + 8*g) ^ SW(vrow)]);
            acc[tc] = __builtin_amdgcn_mfma_f32_16x16x32_bf16(as, bv, acc[tc], 0, 0, 0);
        }
    }
    __syncthreads();   // (b) StT visible; Sbh-A reads done

    // ---- S pass B: cols 64..127 (Kb rows 64..127) -> Sbh (local col-64) ----
#pragma unroll
    for (int tc = 4; tc < 8; ++tc) {
        f32x4 sacc = {0.f,0.f,0.f,0.f};
#pragma unroll
        for (int ks = 0; ks < 2; ++ks) {
            short8 bk = *(const short8*)(&Kb[16*tc + l15][32*ks + 8*g]);
            sacc = __builtin_amdgcn_mfma_f32_16x16x32_bf16(aq[ks], bk, sacc, 0, 0, 0);
        }
        const int colg = 16*tc + l15;
#pragma unroll
        for (int e = 0; e < 4; ++e) {
            const float sv = (colg <= rowb + e) ? sacc[e] : 0.0f;
            Sbh[rowb + e][colg - 64] = f2bf(sv);
        }
    }

    // ---- O += Q . State^T (kd 0,1) ----
#pragma unroll
    for (int kd = 0; kd < 2; ++kd) {
#pragma unroll
        for (int tc = 0; tc < 5; ++tc) {
            int srow = 16*tc + l15;
            if (srow > 64) srow = 64;              // clamp into ksum row
            short8 bs = *(const short8*)(&StT[srow][32*kd + 8*g]);
            acc[tc] = __builtin_amdgcn_mfma_f32_16x16x32_bf16(aq[kd], bs, acc[tc], 0, 0, 0);
        }
    }
    __syncthreads();   // (c) Sbh-B ready

    // ---- O += S_B.V (kj 2,3) ----
#pragma unroll
    for (int kj = 2; kj < 4; ++kj) {
        short8 as = *(const short8*)(&Sbh[16*w + l15][32*(kj-2) + 8*g]);
#pragma unroll
        for (int tc = 0; tc < 5; ++tc) {
            int vrow = 16*tc + l15;
            if (vrow > 64) vrow = 64;
            short8 bv = *(const short8*)(&VT[vrow][(32*kj + 8*g) ^ SW(vrow)]);
            acc[tc] = __builtin_amdgcn_mfma_f32_16x16x32_bf16(as, bv, acc[tc], 0, 0, 0);
        }
    }

    // ---- epilogue ----
    float rn[4];
#pragma unroll
    for (int e = 0; e < 4; ++e) rn[e] = 1.0f / acc[4][e];
    const int rowg = c*CC + rowb;
#pragma unroll
    for (int e = 0; e < 4; ++e) {
        float* orow = out + (((size_t)b*SS + rowg + e)*HH + h)*DD + l15;
#pragma unroll
        for (int tc = 0; tc < 4; ++tc) orow[16*tc] = acc[tc][e] * rn[e];
    }
}

// ===========================================================================
// Fallback path: verbatim R15 3-kernel pipeline (30.0 µs, proven).
// ===========================================================================
__global__ __launch_bounds__(512) void k_state_fb(const float* __restrict__ qk,
                                                  const float* __restrict__ v,
                                                  short* __restrict__ rec_g) {
    const int blk = blockIdx.x;
    const int c   = blk % NCH;
    const int bh  = blk / NCH;
    const int b = bh / HH, h = bh % HH;
    const int tid = threadIdx.x;
    const int w   = tid >> 6;
    const int l   = tid & 63;
    const int l15 = l & 15;
    const int g   = l >> 4;

    __shared__ short KT[64][136];
    __shared__ short VT[65][136];

#pragma unroll
    for (int it = 0; it < 2; ++it) {
        const int pi   = tid + it*512;
        const int r    = pi >> 4;
        const int col4 = (pi & 15) * 4;
        const int s0 = c*CC + 2*r;
        const float* kp = qk + ((((size_t)b*SS + s0)*2 + 1)*HH + h)*DD + col4;
        float4 k0 = *(const float4*)kp;
        float4 k1 = *(const float4*)(kp + 2*HH*DD);
        const float* vp = v + (((size_t)b*SS + s0)*HH + h)*DD + col4;
        float4 v0 = *(const float4*)vp;
        float4 v1 = *(const float4*)(vp + HH*DD);
        const int s2 = 2*r;
        *(unsigned*)(&KT[col4+0][s2 ^ SW(col4+0)]) = pack2(elu1(k0.x), elu1(k1.x));
        *(unsigned*)(&KT[col4+1][s2 ^ SW(col4+1)]) = pack2(elu1(k0.y), elu1(k1.y));
        *(unsigned*)(&KT[col4+2][s2 ^ SW(col4+2)]) = pack2(elu1(k0.z), elu1(k1.z));
        *(unsigned*)(&KT[col4+3][s2 ^ SW(col4+3)]) = pack2(elu1(k0.w), elu1(k1.w));
        *(unsigned*)(&VT[col4+0][s2 ^ SW(col4+0)]) = pack2(v0.x, v1.x);
        *(unsigned*)(&VT[col4+1][s2 ^ SW(col4+1)]) = pack2(v0.y, v1.y);
        *(unsigned*)(&VT[col4+2][s2 ^ SW(col4+2)]) = pack2(v0.z, v1.z);
        *(unsigned*)(&VT[col4+3][s2 ^ SW(col4+3)]) = pack2(v0.w, v1.w);
    }
    if (tid < 64) *(unsigned*)(&VT[64][2*tid]) = 0x3F803F80u;
    __syncthreads();

    const int dtile = w & 3;
    const int half  = w >> 2;
    const int nrt   = half ? 2 : 3;
    const int rt0   = half ? 3 : 0;
    f32x4 acc1[3];
#pragma unroll
    for (int i = 0; i < 3; ++i) acc1[i] = (f32x4){0.f,0.f,0.f,0.f};
    const int krow = 16*dtile + l15;
#pragma unroll
    for (int ks = 0; ks < 4; ++ks) {
        const int cb = 32*ks + 8*g;
        short8 bk = *(const short8*)(&KT[krow][cb ^ SW(krow)]);
#pragma unroll
        for (int i = 0; i < 3; ++i) {
            if (i < nrt) {
                int arow = 16*(rt0 + i) + l15;
                if (arow > 64) arow = 64;
                short8 a = *(const short8*)(&VT[arow][cb ^ SW(arow)]);
                acc1[i] = __builtin_amdgcn_mfma_f32_16x16x32_bf16(a, bk, acc1[i], 0, 0, 0);
            }
        }
    }
    short* rec = rec_g + (size_t)blk * RECF;
#pragma unroll
    for (int i = 0; i < 3; ++i) {
        if (i < nrt) {
            const int rt = rt0 + i;
            if (rt < 4) {
#pragma unroll
                for (int e = 0; e < 4; ++e)
                    rec[(16*rt + 4*g + e)*DD + 16*dtile + l15] = f2bf(acc1[i][e]);
            } else if (g == 0) {
                rec[4096 + 16*dtile + l15] = f2bf(acc1[i][0]);
            }
        }
    }
}

__global__ __launch_bounds__(256) void k_scan_fb(const short* __restrict__ rec_g,
                                                 short* __restrict__ stp_g) {
    const int bh    = blockIdx.x >> 4;
    const int slice = blockIdx.x & 15;
#pragma unroll 1
    for (int ee = threadIdx.x; ee < 260; ee += 256) {
        const int elem = slice*260 + ee;
        float vals[16];
#pragma unroll
        for (int c2 = 0; c2 < 16; ++c2)
            vals[c2] = bf2f(rec_g[(size_t)(bh*NCH + c2)*RECF + elem]);
        float pref = 0.0f;
#pragma unroll
        for (int c2 = 0; c2 < 16; ++c2) {
            stp_g[(size_t)(bh*NCH + c2)*RECF + elem] = f2bf(pref);
            pref += vals[c2];
        }
    }
}

__global__ __launch_bounds__(512) void k_out_fb(const float* __restrict__ qk,
                                                const float* __restrict__ v,
                                                const short* __restrict__ stp_g,
                                                float* __restrict__ out) {
    const int blk = blockIdx.x;
    const int c   = blk % NCH;
    const int bh  = blk / NCH;
    const int b = bh / HH, h = bh % HH;
    const int tid = threadIdx.x;
    const int w   = tid >> 6;
    const int l   = tid & 63;
    const int l15 = l & 15;
    const int g   = l >> 4;

    __shared__ short Kbh[64][64];
    __shared__ short Sbh[128][72];
    __shared__ short StT[65][72];
    __shared__ short VT[65][136];

#pragma unroll
    for (int it = 0; it < 2; ++it) {
        const int pi   = tid + it*512;
        const int r    = pi >> 4;
        const int col4 = (pi & 15) * 4;
        const int s0 = c*CC + 2*r;
        const float* vp = v + (((size_t)b*SS + s0)*HH + h)*DD + col4;
        float4 v0 = *(const float4*)vp;
        float4 v1 = *(const float4*)(vp + HH*DD);
        const int s2 = 2*r;
        *(unsigned*)(&VT[col4+0][s2 ^ SW(col4+0)]) = pack2(v0.x, v1.x);
        *(unsigned*)(&VT[col4+1][s2 ^ SW(col4+1)]) = pack2(v0.y, v1.y);
        *(unsigned*)(&VT[col4+2][s2 ^ SW(col4+2)]) = pack2(v0.z, v1.z);
        *(unsigned*)(&VT[col4+3][s2 ^ SW(col4+3)]) = pack2(v0.w, v1.w);
    }
    if (tid < 64) *(unsigned*)(&VT[64][2*tid]) = 0x3F803F80u;

#pragma unroll
    for (int it = 0; it < 2; ++it) {
        const int f    = tid + it*512;
        const int row  = f >> 4;
        const int col4 = (f & 15) * 4;
        const int s = c*CC + row;
        float4 kq = *(const float4*)(qk + ((((size_t)b*SS + s)*2 + 1)*HH + h)*DD + col4);
        short4 kb;
        kb.x = f2bf(elu1(kq.x)); kb.y = f2bf(elu1(kq.y));
        kb.z = f2bf(elu1(kq.z)); kb.w = f2bf(elu1(kq.w));
        *(short4*)(&Kbh[row][col4 ^ SK(row)]) = kb;
    }

    short4 kbB[2];
#pragma unroll
    for (int it = 0; it < 2; ++it) {
        const int f    = tid + it*512;
        const int row  = 64 + (f >> 4);
        const int col4 = (f & 15) * 4;
        const int s = c*CC + row;
        float4 kq = *(const float4*)(qk + ((((size_t)b*SS + s)*2 + 1)*HH + h)*DD + col4);
        kbB[it].x = f2bf(elu1(kq.x)); kbB[it].y = f2bf(elu1(kq.y));
        kbB[it].z = f2bf(elu1(kq.z)); kbB[it].w = f2bf(elu1(kq.w));
    }

    {
        const short* stp = stp_g + (size_t)blk * RECF;
        short8 st0 = *(const short8*)(stp + tid*8);
        *(short8*)(&StT[tid >> 3][(tid & 7) * 8]) = st0;
        if (tid < 8) {
            short8 st1 = *(const short8*)(stp + 4096 + tid*8);
            *(short8*)(&StT[64][tid * 8]) = st1;
        }
    }

    const int qrow = 16*w + l15;
    const float* qp = qk + ((((size_t)b*SS + (c*CC + qrow))*2 + 0)*HH + h)*DD;
    short8 aq[2];
#pragma unroll
    for (int ks = 0; ks < 2; ++ks) {
        const int k0 = 32*ks + 8*g;
        float4 t0 = *(const float4*)(qp + k0);
        float4 t1 = *(const float4*)(qp + k0 + 4);
        short8 a;
        a[0] = f2bf(elu1(t0.x)); a[1] = f2bf(elu1(t0.y));
        a[2] = f2bf(elu1(t0.z)); a[3] = f2bf(elu1(t0.w));
        a[4] = f2bf(elu1(t1.x)); a[5] = f2bf(elu1(t1.y));
        a[6] = f2bf(elu1(t1.z)); a[7] = f2bf(elu1(t1.w));
        aq[ks] = a;
    }
    __syncthreads();

    const int rowb = 16*w + 4*g;

#pragma unroll
    for (int tc = 0; tc < 4; ++tc) {
        const int kr = 16*tc + l15;
        f32x4 sacc = {0.f,0.f,0.f,0.f};
#pragma unroll
        for (int ks = 0; ks < 2; ++ks) {
            short8 bk = *(const short8*)(&Kbh[kr][(32*ks + 8*g) ^ SK(kr)]);
            sacc = __builtin_amdgcn_mfma_f32_16x16x32_bf16(aq[ks], bk, sacc, 0, 0, 0);
        }
        const int colg = 16*tc + l15;
#pragma unroll
        for (int e = 0; e < 4; ++e) {
            const float sv = (colg <= rowb + e) ? sacc[e] : 0.0f;
            Sbh[rowb + e][colg] = f2bf(sv);
        }
    }
    __syncthreads();

#pragma unroll
    for (int it = 0; it < 2; ++it) {
        const int f    = tid + it*512;
        const int row  = f >> 4;
        const int col4 = (f & 15) * 4;
        *(short4*)(&Kbh[row][col4 ^ SK(row)]) = kbB[it];
    }

    f32x4 acc[5];
#pragma unroll
    for (int t = 0; t < 5; ++t) acc[t] = (f32x4){0.f,0.f,0.f,0.f};
#pragma unroll
    for (int kj = 0; kj < 2; ++kj) {
        short8 as = *(const short8*)(&Sbh[16*w + l15][32*kj + 8*g]);
#pragma unroll
        for (int tc = 0; tc < 5; ++tc) {
            int vrow = 16*tc + l15;
            if (vrow > 64) vrow = 64;
            short8 bv = *(const short8*)(&VT[vrow][(32*kj + 8*g) ^ SW(vrow)]);
            acc[tc] = __builtin_amdgcn_mfma_f32_16x16x32_bf16(as, bv, acc[tc], 0, 0, 0);
        }
    }
#pragma unroll
    for (int kd = 0; kd < 2; ++kd) {
#pragma unroll
        for (int tc = 0; tc < 5; ++tc) {
            int srow = 16*tc + l15;
            if (srow > 64) srow = 64;
            short8 bs = *(const short8*)(&StT[srow][32*kd + 8*g]);
            acc[tc] = __builtin_amdgcn_mfma_f32_16x16x32_bf16(aq[kd], bs, acc[tc], 0, 0, 0);
        }
    }
    __syncthreads();

#pragma unroll
    for (int tc = 4; tc < 8; ++tc) {
        const int kr = 16*(tc-4) + l15;
        f32x4 sacc = {0.f,0.f,0.f,0.f};
#pragma unroll
        for (int ks = 0; ks < 2; ++ks) {
            short8 bk = *(const short8*)(&Kbh[kr][(32*ks + 8*g) ^ SK(kr)]);
            sacc = __builtin_amdgcn_mfma_f32_16x16x32_bf16(aq[ks], bk, sacc, 0, 0, 0);
        }
        const int colg = 16*tc + l15;
#pragma unroll
        for (int e = 0; e < 4; ++e) {
            const float sv = (colg <= rowb + e) ? sacc[e] : 0.0f;
            Sbh[rowb + e][colg - 64] = f2bf(sv);
        }
    }
    __syncthreads();

#pragma unroll
    for (int kj = 2; kj < 4; ++kj) {
        short8 as = *(const short8*)(&Sbh[16*w + l15][32*(kj-2) + 8*g]);
#pragma unroll
        for (int tc = 0; tc < 5; ++tc) {
            int vrow = 16*tc + l15;
            if (vrow > 64) vrow = 64;
            short8 bv = *(const short8*)(&VT[vrow][(32*kj + 8*g) ^ SW(vrow)]);
            acc[tc] = __builtin_amdgcn_mfma_f32_16x16x32_bf16(as, bv, acc[tc], 0, 0, 0);
        }
    }

    float rn[4];
#pragma unroll
    for (int e = 0; e < 4; ++e) rn[e] = 1.0f / acc[4][e];
    const int rowg = c*CC + rowb;
#pragma unroll
    for (int e = 0; e < 4; ++e) {
        float* orow = out + (((size_t)b*SS + rowg + e)*HH + h)*DD + l15;
#pragma unroll
        for (int tc = 0; tc < 4; ++tc) orow[16*tc] = acc[tc][e] * rn[e];
    }
}

// ---------------------------------------------------------------------------
extern "C" void kernel_launch(void* const* d_in, const int* in_sizes, int n_in,
                              void* d_out, int out_size, void* d_ws, size_t ws_size,
                              hipStream_t stream) {
    const float* qk = (const float*)d_in[0];
    const float* v  = (const float*)d_in[1];
    float* out = (float*)d_out;

    short* rec_g = (short*)d_ws;                   // 512*4160 bf16 = 4.26 MB
    short* stp_g = rec_g + (size_t)NCHK * RECF;    // fallback only

    void* args[] = { (void*)&qk, (void*)&v, (void*)&rec_g, (void*)&out };
    hipError_t le = hipLaunchCooperativeKernel((const void*)k_fused, dim3(NCHK),
                                               dim3(512), args, 0, stream);
    if (le != hipSuccess) {
        k_state_fb<<<dim3(NCHK), dim3(512), 0, stream>>>(qk, v, rec_g);
        k_scan_fb <<<dim3(NCHK), dim3(256), 0, stream>>>(rec_g, stp_g);
        k_out_fb  <<<dim3(NCHK), dim3(512), 0, stream>>>(qk, v, stp_g, out);
    }
}

// Round 21
// 30.118 us; speedup vs baseline: 9.4812x; 9.2581x over previous
//
#include <hip/hip_runtime.h>

// Problem constants (B,S,H,D fixed by the reference)
#define BB   2
#define SS   2048
#define HH   16
#define DD   64
#define CC   128               // chunk length
#define NCH  (SS/CC)           // 16 chunks per (b,h)
#define RECF (DD*DD + DD)      // 4160 elems per record: State^T rows 0..63 + ksum row 64
#define BHN  (BB*HH)           // 32
#define NCHK (BHN*NCH)         // 512 chunk-blocks

typedef __attribute__((ext_vector_type(8))) short short8;
typedef __attribute__((ext_vector_type(4))) float f32x4;

// XOR swizzle of the s-index (units of 8 shorts) by LDS row (stride-136 tiles).
#define SW(r) ((((r) >> 3) & 7) << 3)
// XOR swizzle for the pad-free Kbh[64][64] tile in k_out.
#define SK(r) (((r) & 7) << 3)

__device__ __forceinline__ float elu1(float x) {
    return x > 0.0f ? x + 1.0f : __expf(x);
}
__device__ __forceinline__ short f2bf(float f) {
    union { float f; unsigned u; } x; x.f = f;
    unsigned r = x.u + 0x7FFFu + ((x.u >> 16) & 1u);   // RNE
    return (short)(r >> 16);
}
__device__ __forceinline__ float bf2f(short s) {
    union { unsigned u; float f; } x; x.u = ((unsigned)(unsigned short)s) << 16;
    return x.f;
}
// pack two bf16 into one dword: lo -> short[0], hi -> short[1]
__device__ __forceinline__ unsigned pack2(float lo, float hi) {
    return (unsigned)(unsigned short)f2bf(lo)
         | ((unsigned)(unsigned short)f2bf(hi) << 16);
}

// ---------------------------------------------------------------------------
// Kernel 1: per-chunk State^T (+ksum row) = [V^T; ones] . K -> rec_g (bf16).
// Packed row-pair dword transpose writes (conflict-free).
// ---------------------------------------------------------------------------
__global__ __launch_bounds__(512) void k_state(const float* __restrict__ qk,
                                               const float* __restrict__ v,
                                               short* __restrict__ rec_g) {
    const int blk = blockIdx.x;
    const int c   = blk % NCH;
    const int bh  = blk / NCH;
    const int b = bh / HH, h = bh % HH;
    const int tid = threadIdx.x;
    const int w   = tid >> 6;
    const int l   = tid & 63;
    const int l15 = l & 15;
    const int g   = l >> 4;

    __shared__ short KT[64][136];   // K^T, swizzled cols
    __shared__ short VT[65][136];   // V^T + ones row 64

#pragma unroll
    for (int it = 0; it < 2; ++it) {
        const int pi   = tid + it*512;      // 0..1023
        const int r    = pi >> 4;           // row-pair index
        const int col4 = (pi & 15) * 4;     // d base
        const int s0 = c*CC + 2*r;
        const float* kp = qk + ((((size_t)b*SS + s0)*2 + 1)*HH + h)*DD + col4;
        float4 k0 = *(const float4*)kp;
        float4 k1 = *(const float4*)(kp + 2*HH*DD);
        const float* vp = v + (((size_t)b*SS + s0)*HH + h)*DD + col4;
        float4 v0 = *(const float4*)vp;
        float4 v1 = *(const float4*)(vp + HH*DD);
        const int s2 = 2*r;
        *(unsigned*)(&KT[col4+0][s2 ^ SW(col4+0)]) = pack2(elu1(k0.x), elu1(k1.x));
        *(unsigned*)(&KT[col4+1][s2 ^ SW(col4+1)]) = pack2(elu1(k0.y), elu1(k1.y));
        *(unsigned*)(&KT[col4+2][s2 ^ SW(col4+2)]) = pack2(elu1(k0.z), elu1(k1.z));
        *(unsigned*)(&KT[col4+3][s2 ^ SW(col4+3)]) = pack2(elu1(k0.w), elu1(k1.w));
        *(unsigned*)(&VT[col4+0][s2 ^ SW(col4+0)]) = pack2(v0.x, v1.x);
        *(unsigned*)(&VT[col4+1][s2 ^ SW(col4+1)]) = pack2(v0.y, v1.y);
        *(unsigned*)(&VT[col4+2][s2 ^ SW(col4+2)]) = pack2(v0.z, v1.z);
        *(unsigned*)(&VT[col4+3][s2 ^ SW(col4+3)]) = pack2(v0.w, v1.w);
    }
    if (tid < 64) *(unsigned*)(&VT[64][2*tid]) = 0x3F803F80u;   // ones row (SW(64)==0)
    __syncthreads();

    const int dtile = w & 3;
    const int half  = w >> 2;
    const int nrt   = half ? 2 : 3;
    const int rt0   = half ? 3 : 0;
    f32x4 acc1[3];
#pragma unroll
    for (int i = 0; i < 3; ++i) acc1[i] = (f32x4){0.f,0.f,0.f,0.f};
    const int krow = 16*dtile + l15;
#pragma unroll
    for (int ks = 0; ks < 4; ++ks) {
        const int cb = 32*ks + 8*g;
        short8 bk = *(const short8*)(&KT[krow][cb ^ SW(krow)]);
#pragma unroll
        for (int i = 0; i < 3; ++i) {
            if (i < nrt) {
                int arow = 16*(rt0 + i) + l15;
                if (arow > 64) arow = 64;          // clamp into ones row
                short8 a = *(const short8*)(&VT[arow][cb ^ SW(arow)]);
                acc1[i] = __builtin_amdgcn_mfma_f32_16x16x32_bf16(a, bk, acc1[i], 0, 0, 0);
            }
        }
    }
    short* rec = rec_g + (size_t)blk * RECF;
#pragma unroll
    for (int i = 0; i < 3; ++i) {
        if (i < nrt) {
            const int rt = rt0 + i;
            if (rt < 4) {
#pragma unroll
                for (int e = 0; e < 4; ++e)
                    rec[(16*rt + 4*g + e)*DD + 16*dtile + l15] = f2bf(acc1[i][e]);
            } else if (g == 0) {
                rec[4096 + 16*dtile + l15] = f2bf(acc1[i][0]);   // ksum row
            }
        }
    }
}

// ---------------------------------------------------------------------------
// Kernel 2: exclusive prefix scan over chunks (bf16 in/out). All 16 chunk
// loads in flight; ascending-order fp32 adds.
// ---------------------------------------------------------------------------
__global__ __launch_bounds__(256) void k_scan(const short* __restrict__ rec_g,
                                              short* __restrict__ stp_g) {
    const int bh    = blockIdx.x >> 4;
    const int slice = blockIdx.x & 15;
#pragma unroll 1
    for (int ee = threadIdx.x; ee < 260; ee += 256) {
        const int elem = slice*260 + ee;
        float vals[16];
#pragma unroll
        for (int c2 = 0; c2 < 16; ++c2)
            vals[c2] = bf2f(rec_g[(size_t)(bh*NCH + c2)*RECF + elem]);
        float pref = 0.0f;
#pragma unroll
        for (int c2 = 0; c2 < 16; ++c2) {
            stp_g[(size_t)(bh*NCH + c2)*RECF + elem] = f2bf(pref);
            pref += vals[c2];
        }
    }
}

// ---------------------------------------------------------------------------
// Kernel 3: O = [S | Q] . [V;ones ; State_prefix^T;ksum], S = mask(Q K^T).
// Half-K tile staged twice; LDS 53,664 B. No launch-bounds min.
// ---------------------------------------------------------------------------
__global__ __launch_bounds__(512) void k_out(const float* __restrict__ qk,
                                             const float* __restrict__ v,
                                             const short* __restrict__ stp_g,
                                             float* __restrict__ out) {
    const int blk = blockIdx.x;
    const int c   = blk % NCH;
    const int bh  = blk / NCH;
    const int b = bh / HH, h = bh % HH;
    const int tid = threadIdx.x;
    const int w   = tid >> 6;
    const int l   = tid & 63;
    const int l15 = l & 15;
    const int g   = l >> 4;

    __shared__ short Kbh[64][64];   // half K tile, XOR-swizzled   8192 B
    __shared__ short Sbh[128][72];  // score half (two passes)    18432 B
    __shared__ short StT[65][72];   // prefix State^T + ksum row   9360 B
    __shared__ short VT[65][136];   // V^T + ones row 64          17680 B

    // ---- V staging: packed row-pair dword transpose ----
#pragma unroll
    for (int it = 0; it < 2; ++it) {
        const int pi   = tid + it*512;      // 0..1023
        const int r    = pi >> 4;
        const int col4 = (pi & 15) * 4;
        const int s0 = c*CC + 2*r;
        const float* vp = v + (((size_t)b*SS + s0)*HH + h)*DD + col4;
        float4 v0 = *(const float4*)vp;
        float4 v1 = *(const float4*)(vp + HH*DD);
        const int s2 = 2*r;
        *(unsigned*)(&VT[col4+0][s2 ^ SW(col4+0)]) = pack2(v0.x, v1.x);
        *(unsigned*)(&VT[col4+1][s2 ^ SW(col4+1)]) = pack2(v0.y, v1.y);
        *(unsigned*)(&VT[col4+2][s2 ^ SW(col4+2)]) = pack2(v0.z, v1.z);
        *(unsigned*)(&VT[col4+3][s2 ^ SW(col4+3)]) = pack2(v0.w, v1.w);
    }
    if (tid < 64) *(unsigned*)(&VT[64][2*tid]) = 0x3F803F80u;   // ones row

    // ---- Kbh pass-A staging (K rows 0..63) ----
#pragma unroll
    for (int it = 0; it < 2; ++it) {
        const int f    = tid + it*512;      // 0..1023
        const int row  = f >> 4;            // 0..63
        const int col4 = (f & 15) * 4;
        const int s = c*CC + row;
        float4 kq = *(const float4*)(qk + ((((size_t)b*SS + s)*2 + 1)*HH + h)*DD + col4);
        short4 kb;
        kb.x = f2bf(elu1(kq.x)); kb.y = f2bf(elu1(kq.y));
        kb.z = f2bf(elu1(kq.z)); kb.w = f2bf(elu1(kq.w));
        *(short4*)(&Kbh[row][col4 ^ SK(row)]) = kb;
    }

    // ---- Kbh pass-B data (K rows 64..127): load+convert now, LDS-write later
    short4 kbB[2];
#pragma unroll
    for (int it = 0; it < 2; ++it) {
        const int f    = tid + it*512;
        const int row  = 64 + (f >> 4);     // 64..127
        const int col4 = (f & 15) * 4;
        const int s = c*CC + row;
        float4 kq = *(const float4*)(qk + ((((size_t)b*SS + s)*2 + 1)*HH + h)*DD + col4);
        kbB[it].x = f2bf(elu1(kq.x)); kbB[it].y = f2bf(elu1(kq.y));
        kbB[it].z = f2bf(elu1(kq.z)); kbB[it].w = f2bf(elu1(kq.w));
    }

    // ---- prefix record: direct copy into StT (no accumulate) ----
    {
        const short* stp = stp_g + (size_t)blk * RECF;
        short8 st0 = *(const short8*)(stp + tid*8);
        *(short8*)(&StT[tid >> 3][(tid & 7) * 8]) = st0;
        if (tid < 8) {
            short8 st1 = *(const short8*)(stp + 4096 + tid*8);
            *(short8*)(&StT[64][tid * 8]) = st1;
        }
    }

    // ---- Q fragments (elu1 -> bf16) ----
    const int qrow = 16*w + l15;
    const float* qp = qk + ((((size_t)b*SS + (c*CC + qrow))*2 + 0)*HH + h)*DD;
    short8 aq[2];
#pragma unroll
    for (int ks = 0; ks < 2; ++ks) {
        const int k0 = 32*ks + 8*g;
        float4 t0 = *(const float4*)(qp + k0);
        float4 t1 = *(const float4*)(qp + k0 + 4);
        short8 a;
        a[0] = f2bf(elu1(t0.x)); a[1] = f2bf(elu1(t0.y));
        a[2] = f2bf(elu1(t0.z)); a[3] = f2bf(elu1(t0.w));
        a[4] = f2bf(elu1(t1.x)); a[5] = f2bf(elu1(t1.y));
        a[6] = f2bf(elu1(t1.z)); a[7] = f2bf(elu1(t1.w));
        aq[ks] = a;
    }
    __syncthreads();   // sync1: VT, Kbh-A, StT ready

    const int rowb = 16*w + 4*g;

    // ---- S pass A: global cols 0..63 from Kbh (rows 0..63) ----
#pragma unroll
    for (int tc = 0; tc < 4; ++tc) {
        const int kr = 16*tc + l15;
        f32x4 sacc = {0.f,0.f,0.f,0.f};
#pragma unroll
        for (int ks = 0; ks < 2; ++ks) {
            short8 bk = *(const short8*)(&Kbh[kr][(32*ks + 8*g) ^ SK(kr)]);
            sacc = __builtin_amdgcn_mfma_f32_16x16x32_bf16(aq[ks], bk, sacc, 0, 0, 0);
        }
        const int colg = 16*tc + l15;
#pragma unroll
        for (int e = 0; e < 4; ++e) {
            const float sv = (colg <= rowb + e) ? sacc[e] : 0.0f;
            Sbh[rowb + e][colg] = f2bf(sv);
        }
    }
    __syncthreads();   // sync2: Sbh-A ready, Kbh-A reads done

    // ---- Kbh pass-B LDS writes (hidden under the MFMAs below) ----
#pragma unroll
    for (int it = 0; it < 2; ++it) {
        const int f    = tid + it*512;
        const int row  = f >> 4;            // local row 0..63 (global 64..127)
        const int col4 = (f & 15) * 4;
        *(short4*)(&Kbh[row][col4 ^ SK(row)]) = kbB[it];
    }

    // ---- O = S_A.V (kj 0,1) + Q.State^T (kd 0,1); tile 4 = denominator ----
    f32x4 acc[5];
#pragma unroll
    for (int t = 0; t < 5; ++t) acc[t] = (f32x4){0.f,0.f,0.f,0.f};
#pragma unroll
    for (int kj = 0; kj < 2; ++kj) {
        short8 as = *(const short8*)(&Sbh[16*w + l15][32*kj + 8*g]);
#pragma unroll
        for (int tc = 0; tc < 5; ++tc) {
            int vrow = 16*tc + l15;
            if (vrow > 64) vrow = 64;              // clamp into ones row
            short8 bv = *(const short8*)(&VT[vrow][(32*kj + 8*g) ^ SW(vrow)]);
            acc[tc] = __builtin_amdgcn_mfma_f32_16x16x32_bf16(as, bv, acc[tc], 0, 0, 0);
        }
    }
#pragma unroll
    for (int kd = 0; kd < 2; ++kd) {
#pragma unroll
        for (int tc = 0; tc < 5; ++tc) {
            int srow = 16*tc + l15;
            if (srow > 64) srow = 64;              // clamp into ksum row
            short8 bs = *(const short8*)(&StT[srow][32*kd + 8*g]);
            acc[tc] = __builtin_amdgcn_mfma_f32_16x16x32_bf16(aq[kd], bs, acc[tc], 0, 0, 0);
        }
    }
    __syncthreads();   // sync3: Kbh-B visible; Sbh-A reads done

    // ---- S pass B: global cols 64..127 from Kbh (rows 64..127) ----
#pragma unroll
    for (int tc = 4; tc < 8; ++tc) {
        const int kr = 16*(tc-4) + l15;
        f32x4 sacc = {0.f,0.f,0.f,0.f};
#pragma unroll
        for (int ks = 0; ks < 2; ++ks) {
            short8 bk = *(const short8*)(&Kbh[kr][(32*ks + 8*g) ^ SK(kr)]);
            sacc = __builtin_amdgcn_mfma_f32_16x16x32_bf16(aq[ks], bk, sacc, 0, 0, 0);
        }
        const int colg = 16*tc + l15;
#pragma unroll
        for (int e = 0; e < 4; ++e) {
            const float sv = (colg <= rowb + e) ? sacc[e] : 0.0f;
            Sbh[rowb + e][colg - 64] = f2bf(sv);
        }
    }
    __syncthreads();   // sync4: Sbh-B ready

    // ---- O += S_B.V (kj 2,3; global s = 64 + local) ----
#pragma unroll
    for (int kj = 2; kj < 4; ++kj) {
        short8 as = *(const short8*)(&Sbh[16*w + l15][32*(kj-2) + 8*g]);
#pragma unroll
        for (int tc = 0; tc < 5; ++tc) {
            int vrow = 16*tc + l15;
            if (vrow > 64) vrow = 64;
            short8 bv = *(const short8*)(&VT[vrow][(32*kj + 8*g) ^ SW(vrow)]);
            acc[tc] = __builtin_amdgcn_mfma_f32_16x16x32_bf16(as, bv, acc[tc], 0, 0, 0);
        }
    }

    // ---- epilogue: acc[4][e] IS the denominator in every lane ----
    float rn[4];
#pragma unroll
    for (int e = 0; e < 4; ++e) rn[e] = 1.0f / acc[4][e];
    const int rowg = c*CC + rowb;
#pragma unroll
    for (int e = 0; e < 4; ++e) {
        float* orow = out + (((size_t)b*SS + rowg + e)*HH + h)*DD + l15;
#pragma unroll
        for (int tc = 0; tc < 4; ++tc) orow[16*tc] = acc[tc][e] * rn[e];
    }
}

// ---------------------------------------------------------------------------
extern "C" void kernel_launch(void* const* d_in, const int* in_sizes, int n_in,
                              void* d_out, int out_size, void* d_ws, size_t ws_size,
                              hipStream_t stream) {
    const float* qk = (const float*)d_in[0];
    const float* v  = (const float*)d_in[1];
    float* out = (float*)d_out;

    short* rec_g = (short*)d_ws;                   // 512*4160 bf16 = 4.26 MB
    short* stp_g = rec_g + (size_t)NCHK * RECF;    // 512*4160 bf16 = 4.26 MB

    k_state<<<dim3(NCHK), dim3(512), 0, stream>>>(qk, v, rec_g);
    k_scan <<<dim3(NCHK), dim3(256), 0, stream>>>(rec_g, stp_g);
    k_out  <<<dim3(NCHK), dim3(512), 0, stream>>>(qk, v, stp_g, out);
}